// Round 2
// baseline (5341.264 us; speedup 1.0000x reference)
//
#include <hip/hip_runtime.h>
#include <math.h>

#define Bn 128
#define Tn 256
#define Fn 36
#define Hn 128
#define F2n 72
#define G4 512
#define BTFn (Bn*Tn*Fn)

// workspace layout (floats) — keep prior offsets (well within ws_size)
#define INVD_OFF 0
#define LOSS_OFF 102656
#define IMP_OFF  103040

__device__ __forceinline__ float sigmoid_f(float x) {
    return __builtin_amdgcn_rcpf(1.f + __expf(-x));
}
__device__ __forceinline__ float tanh_f(float x) {
    return fmaf(2.f, __builtin_amdgcn_rcpf(1.f + __expf(-2.f * x)), -1.f);
}

// ---------------- prep: inv-denom per t ----------------
__global__ void prep_kernel(const float* __restrict__ data,
                            float* __restrict__ ws) {
    int t = blockIdx.x;          // 0..255
    int tid = threadIdx.x;
    __shared__ float red[256];
    float s = 0.f;
    for (int idx = tid; idx < Bn * Fn; idx += 256) {
        int b = idx / Fn, f = idx - b * Fn;
        s += data[((size_t)(b * 24 + 1) * Tn + t) * Fn + f];
    }
    red[tid] = s;
    __syncthreads();
    for (int off = 128; off > 0; off >>= 1) {
        if (tid < off) red[tid] += red[tid + off];
        __syncthreads();
    }
    if (tid == 0) ws[INVD_OFF + t] = 1.f / (red[0] + 1e-5f);
}

// ---------------- main: one block = 2 chains, gate weights in registers ----------------
__global__ __launch_bounds__(512, 2) void rits_main(
    const float* __restrict__ data,
    const float* __restrict__ W_dh, const float* __restrict__ b_dh,
    const float* __restrict__ W_dx, const float* __restrict__ b_dx,
    const float* __restrict__ W_hist, const float* __restrict__ b_hist,
    const float* __restrict__ W_feat, const float* __restrict__ b_feat,
    const float* __restrict__ W_wc, const float* __restrict__ b_wc,
    const float* __restrict__ W_ih, const float* __restrict__ W_hh,
    const float* __restrict__ b_ih, const float* __restrict__ b_hh,
    const float* __restrict__ W_comb,
    float* __restrict__ ws) {

    const int tid = threadIdx.x;
    const int chain0 = blockIdx.x * 2;
    const int chainSel = tid >> 8;      // 0: chain A, 1: chain B
    const int st = tid & 255;
    const int myChain = chain0 + chainSel;
    const int b = myChain / 3, k = myChain - 3 * (myChain / 3);

    __shared__ float Wdh_s[Hn][Fn + 1];
    __shared__ float Whist_s[Fn][Hn + 1];
    __shared__ float Wf_s[Fn][Fn + 1];
    __shared__ float Wwc_s[Fn][F2n + 1];
    __shared__ __align__(16) float h_s[2][Hn];
    __shared__ float gates_s[2][G4];
    __shared__ float in_s[2][5][Fn];            // m,d,rt,tr,se
    __shared__ float xh_s[2][Fn], xc_s[2][Fn], alpha_s[2][Fn], gx_s[2][Fn];
    __shared__ __align__(16) float inp_s[2][F2n];
    __shared__ float bdh_s[Hn];
    __shared__ float bh_s[Fn], bf_s[Fn], bwc_s[Fn], wdxd_s[Fn], bdx_s[Fn];
    __shared__ float invd_s[Tn];

    // ---- one-time LDS staging ----
    for (int i = tid; i < Hn * Fn; i += 512) Wdh_s[i / Fn][i % Fn] = W_dh[i];
    for (int i = tid; i < Fn * Hn; i += 512) Whist_s[i / Hn][i % Hn] = W_hist[i];
    for (int i = tid; i < Fn * Fn; i += 512) {
        int r = i / Fn, c = i - r * Fn;
        Wf_s[r][c] = (r == c) ? 0.f : W_feat[i];
    }
    for (int i = tid; i < Fn * F2n; i += 512) Wwc_s[i / F2n][i % F2n] = W_wc[i];
    if (tid < Hn) bdh_s[tid] = b_dh[tid];
    if (st < Hn) h_s[chainSel][st] = 0.f;
    if (tid < Fn) {
        bh_s[tid] = b_hist[tid]; bf_s[tid] = b_feat[tid]; bwc_s[tid] = b_wc[tid];
        wdxd_s[tid] = W_dx[tid * (Fn + 1)]; bdx_s[tid] = b_dx[tid];
    }
    for (int i = tid; i < Tn; i += 512) invd_s[i] = ws[INVD_OFF + i];

    // ---- gate weights for row j into registers (once) ----
    const int j = tid;
    float4 w[50];
    {
        const float4* wi = (const float4*)(W_ih + j * F2n);   // 288B rows, 16B aligned
        #pragma unroll
        for (int q = 0; q < 18; ++q) w[q] = wi[q];
        const float4* wh = (const float4*)(W_hh + j * Hn);    // 512B rows
        #pragma unroll
        for (int q = 0; q < 32; ++q) w[18 + q] = wh[q];
    }
    const float bias_j = b_ih[j] + b_hh[j];

    // ---- softmax(W_comb) weight for this chain ----
    float wkk;
    {
        float w0 = W_comb[0], w1 = W_comb[1], w2 = W_comb[2];
        float mx = fmaxf(w0, fmaxf(w1, w2));
        float e0 = expf(w0 - mx), e1 = expf(w1 - mx), e2 = expf(w2 - mx);
        wkk = ((k == 0) ? e0 : (k == 1) ? e1 : e2) / (e0 + e1 + e2);
    }

    // ---- input loader roles (threads st in [128,256) load own chain's inputs) ----
    const float* ldsrc0 = nullptr; float* lddst0 = nullptr;
    const float* ldsrc1 = nullptr; float* lddst1 = nullptr;
    if (st >= 128) {
        int idx = st - 128;                       // 0..127
        int which = idx / Fn, f = idx - which * Fn;
        int row = (which == 0) ? 1 : (which == 1) ? 2 : (3 + 3 * k + (which - 2));
        ldsrc0 = data + (size_t)(b * 24 + row) * Tn * Fn + f;
        lddst0 = &in_s[chainSel][which][f];
        int idx2 = idx + 128;                     // 128..255
        if (idx2 < 180) {
            int which2 = idx2 / Fn, f2 = idx2 - which2 * Fn;
            int row2 = (which2 == 0) ? 1 : (which2 == 1) ? 2 : (3 + 3 * k + (which2 - 2));
            ldsrc1 = data + (size_t)(b * 24 + row2) * Tn * Fn + f2;
            lddst1 = &in_s[chainSel][which2][f2];
        }
    }
    // prologue: load t=0 inputs
    if (lddst0) *lddst0 = ldsrc0[0];
    if (lddst1) *lddst1 = ldsrc1[0];

    float c_reg = 0.f;
    float loss_acc = 0.f;
    float gaccA = 0.f, gaccB = 0.f;
    float* imp_b = ws + IMP_OFF + (size_t)(k * Bn + b) * Tn * Fn;

    __syncthreads();

    for (int t = 0; t < Tn; ++t) {
        // ---- P2: decay h; gamma_x ----
        if (st < Hn) {
            float acc = bdh_s[st];
            #pragma unroll
            for (int f = 0; f < Fn; ++f) acc = fmaf(in_s[chainSel][1][f], Wdh_s[st][f], acc);
            h_s[chainSel][st] *= __expf(-fmaxf(acc, 0.f));
        } else if (st < 128 + Fn) {
            int f = st - 128;
            gx_s[chainSel][f] = __expf(-fmaxf(fmaf(in_s[chainSel][1][f], wdxd_s[f], bdx_s[f]), 0.f));
        }
        __syncthreads();

        // ---- P3: x_h/x_c (st<36); alpha (64<=st<100); gate h-part chain A (all) ----
        if (st < Fn) {
            float a0 = bh_s[st], a1 = 0.f, a2 = 0.f, a3 = 0.f;
            #pragma unroll
            for (int hh = 0; hh < Hn; hh += 4) {
                a0 = fmaf(h_s[chainSel][hh],     Whist_s[st][hh],     a0);
                a1 = fmaf(h_s[chainSel][hh + 1], Whist_s[st][hh + 1], a1);
                a2 = fmaf(h_s[chainSel][hh + 2], Whist_s[st][hh + 2], a2);
                a3 = fmaf(h_s[chainSel][hh + 3], Whist_s[st][hh + 3], a3);
            }
            float xh = (a0 + a1) + (a2 + a3);
            xh_s[chainSel][st] = xh;
            float m = in_s[chainSel][0][st], rt = in_s[chainSel][2][st];
            xc_s[chainSel][st] = m * rt + (1.f - m) * xh;
        } else if (st >= 64 && st < 64 + Fn) {
            int g = st - 64;
            float a = bwc_s[g];
            #pragma unroll
            for (int f = 0; f < Fn; ++f) a = fmaf(gx_s[chainSel][f], Wwc_s[g][f], a);
            #pragma unroll
            for (int f = 0; f < Fn; ++f) a = fmaf(in_s[chainSel][0][f], Wwc_s[g][Fn + f], a);
            alpha_s[chainSel][g] = a;
        }
        {   // gate h-part, chain A (broadcast LDS reads)
            const float4* h4 = (const float4*)(&h_s[0][0]);
            float a0 = 0.f, a1 = 0.f, a2 = 0.f, a3 = 0.f;
            #pragma unroll
            for (int q = 0; q < 32; ++q) {
                float4 x = h4[q];
                a0 = fmaf(x.x, w[18 + q].x, a0);
                a1 = fmaf(x.y, w[18 + q].y, a1);
                a2 = fmaf(x.z, w[18 + q].z, a2);
                a3 = fmaf(x.w, w[18 + q].w, a3);
            }
            gaccA = (a0 + a1) + (a2 + a3);
        }
        __syncthreads();

        // ---- P4: z_h/c_h/c_c/inp/loss/imp (st<36); gate h-part chain B (all) ----
        if (st < Fn) {
            float a = bf_s[st];
            #pragma unroll
            for (int f = 0; f < Fn; ++f) a = fmaf(xc_s[chainSel][f], Wf_s[st][f], a);
            float zh = a;
            float al = alpha_s[chainSel][st], xh = xh_s[chainSel][st];
            float ch = al * zh + (1.f - al) * xh;
            float m = in_s[chainSel][0][st], rt = in_s[chainSel][2][st];
            float cc = m * rt + (1.f - m) * ch;
            inp_s[chainSel][st] = cc;
            inp_s[chainSel][Fn + st] = m;
            loss_acc = fmaf((fabsf(rt - xh) + fabsf(rt - zh) + fabsf(rt - ch)) * m,
                            invd_s[t], loss_acc);
            imp_b[t * Fn + st] = cc + in_s[chainSel][4][st] + in_s[chainSel][3][st];
        }
        {   // gate h-part, chain B
            const float4* h4 = (const float4*)(&h_s[1][0]);
            float a0 = 0.f, a1 = 0.f, a2 = 0.f, a3 = 0.f;
            #pragma unroll
            for (int q = 0; q < 32; ++q) {
                float4 x = h4[q];
                a0 = fmaf(x.x, w[18 + q].x, a0);
                a1 = fmaf(x.y, w[18 + q].y, a1);
                a2 = fmaf(x.z, w[18 + q].z, a2);
                a3 = fmaf(x.w, w[18 + q].w, a3);
            }
            gaccB = (a0 + a1) + (a2 + a3);
        }
        __syncthreads();

        // ---- P5: gate inp-part, both chains (all threads, row j) ----
        {
            const float4* xA = (const float4*)(&inp_s[0][0]);
            float a0 = gaccA + bias_j, a1 = 0.f, a2 = 0.f, a3 = 0.f;
            #pragma unroll
            for (int q = 0; q < 18; ++q) {
                float4 x = xA[q];
                a0 = fmaf(x.x, w[q].x, a0);
                a1 = fmaf(x.y, w[q].y, a1);
                a2 = fmaf(x.z, w[q].z, a2);
                a3 = fmaf(x.w, w[q].w, a3);
            }
            gates_s[0][j] = (a0 + a1) + (a2 + a3);
            const float4* xB = (const float4*)(&inp_s[1][0]);
            float b0 = gaccB + bias_j, b1 = 0.f, b2 = 0.f, b3 = 0.f;
            #pragma unroll
            for (int q = 0; q < 18; ++q) {
                float4 x = xB[q];
                b0 = fmaf(x.x, w[q].x, b0);
                b1 = fmaf(x.y, w[q].y, b1);
                b2 = fmaf(x.z, w[q].z, b2);
                b3 = fmaf(x.w, w[q].w, b3);
            }
            gates_s[1][j] = (b0 + b1) + (b2 + b3);
        }
        __syncthreads();

        // ---- P6: LSTM (st<128) ; loaders fetch t+1 inputs (st>=128) ----
        if (st < Hn) {
            float ig = gates_s[chainSel][st],      fg = gates_s[chainSel][Hn + st];
            float gg = gates_s[chainSel][2 * Hn + st], og = gates_s[chainSel][3 * Hn + st];
            c_reg = sigmoid_f(fg) * c_reg + sigmoid_f(ig) * tanh_f(gg);
            h_s[chainSel][st] = sigmoid_f(og) * tanh_f(c_reg);
        } else {
            // t=255 loads t=256: stays within the (b,*) channel block -> safe, unused
            *lddst0 = ldsrc0[(size_t)(t + 1) * Fn];
            if (lddst1) *lddst1 = ldsrc1[(size_t)(t + 1) * Fn];
        }
        __syncthreads();
    }

    // ---- per-chain loss partial (fixed order -> deterministic) ----
    if (st < Fn) gates_s[chainSel][st] = loss_acc;
    __syncthreads();
    if (st == 0) {
        float s = 0.f;
        for (int i = 0; i < Fn; ++i) s += gates_s[chainSel][i];
        ws[LOSS_OFF + myChain] = s * wkk;
    }
}

// ---------------- k-reduction of imputations ----------------
__global__ void impute_reduce(const float* __restrict__ ws,
                              const float* __restrict__ W_comb,
                              float* __restrict__ out) {
    int idx = blockIdx.x * 256 + threadIdx.x;   // < BTFn exactly
    float w0 = W_comb[0], w1 = W_comb[1], w2 = W_comb[2];
    float mx = fmaxf(w0, fmaxf(w1, w2));
    float e0 = expf(w0 - mx), e1 = expf(w1 - mx), e2 = expf(w2 - mx);
    float inv = 1.f / (e0 + e1 + e2);
    const float* imp = ws + IMP_OFF;
    out[1 + idx] = (e0 * imp[idx] + e1 * imp[BTFn + idx] + e2 * imp[2 * BTFn + idx]) * inv;
}

// ---------------- final loss ----------------
__global__ void loss_final(const float* __restrict__ ws,
                           const float* __restrict__ W_comb,
                           float* __restrict__ out) {
    int tid = threadIdx.x;
    __shared__ float red[256];
    const float* lp = ws + LOSS_OFF;
    float s = lp[tid];
    if (tid < 128) s += lp[tid + 256];
    red[tid] = s;
    __syncthreads();
    for (int off = 128; off > 0; off >>= 1) {
        if (tid < off) red[tid] += red[tid + off];
        __syncthreads();
    }
    if (tid == 0) {
        float w0 = W_comb[0], w1 = W_comb[1], w2 = W_comb[2];
        float mx = fmaxf(w0, fmaxf(w1, w2));
        float e0 = expf(w0 - mx), e1 = expf(w1 - mx), e2 = expf(w2 - mx);
        float inv = 1.f / (e0 + e1 + e2);
        float wk0 = e0 * inv, wk1 = e1 * inv, wk2 = e2 * inv;
        float reg = 0.1f * (wk0 * (1.f / 24.f) + wk1 * (1.f / 168.f) + wk2 * (1.f / 720.f));
        out[0] = red[0] + (float)Tn * reg;
    }
}

extern "C" void kernel_launch(void* const* d_in, const int* in_sizes, int n_in,
                              void* d_out, int out_size, void* d_ws, size_t ws_size,
                              hipStream_t stream) {
    const float* data   = (const float*)d_in[0];
    const float* W_dh   = (const float*)d_in[1];
    const float* b_dh   = (const float*)d_in[2];
    const float* W_dx   = (const float*)d_in[3];
    const float* b_dx   = (const float*)d_in[4];
    const float* W_hist = (const float*)d_in[5];
    const float* b_hist = (const float*)d_in[6];
    const float* W_feat = (const float*)d_in[7];
    const float* b_feat = (const float*)d_in[8];
    const float* W_wc   = (const float*)d_in[9];
    const float* b_wc   = (const float*)d_in[10];
    const float* W_ih   = (const float*)d_in[11];
    const float* W_hh   = (const float*)d_in[12];
    const float* b_ih   = (const float*)d_in[13];
    const float* b_hh   = (const float*)d_in[14];
    const float* W_comb = (const float*)d_in[15];
    float* ws = (float*)d_ws;
    float* out = (float*)d_out;

    hipLaunchKernelGGL(prep_kernel, dim3(Tn), dim3(256), 0, stream, data, ws);
    hipLaunchKernelGGL(rits_main, dim3(Bn * 3 / 2), dim3(512), 0, stream,
                       data, W_dh, b_dh, W_dx, b_dx, W_hist, b_hist,
                       W_feat, b_feat, W_wc, b_wc, W_ih, W_hh, b_ih, b_hh, W_comb, ws);
    hipLaunchKernelGGL(impute_reduce, dim3(BTFn / 256), dim3(256), 0, stream, ws, W_comb, out);
    hipLaunchKernelGGL(loss_final, dim3(1), dim3(256), 0, stream, ws, W_comb, out);
}